// Round 7
// baseline (511.874 us; speedup 1.0000x reference)
//
#include <hip/hip_runtime.h>
#include <hip/hip_bf16.h>
#include <math.h>

// Qwen3.5 attention block, bf16-MFMA everywhere.
// cvt(hs), transpose_cvt(w_qkv) -> gemm_bf16(QKV, BK=64) -> vt_transpose ->
// norm_rope_cvt -> flash_attn_mfma v4 (persistent work-queue, single-barrier
// pipelined K-loop, K double-buffered) -> transpose_cvt(w_o) -> gemm_bf16(out).

namespace {
constexpr int kT   = 4096;
constexpr int kHid = 2048;
constexpr int kH   = 16;
constexpr int kHkv = 2;
constexpr int kD   = 128;
constexpr int kNqkv = (2 * kH + 2 * kHkv) * kD;  // 4608 floats per row
constexpr int kQsz  = 2 * kH * kD;               // 4096
constexpr int kRowU = kNqkv * 2;                 // 9216 ushorts per row
constexpr float kEps = 1e-6f;
constexpr float kScale = 0.08838834764831845f;   // 128^-0.5
}

typedef __attribute__((ext_vector_type(8))) short short8;
typedef __attribute__((ext_vector_type(4))) float floatx4;

__device__ inline unsigned short f2bf(float x) {
  unsigned u = __float_as_uint(x);
  u = (u + 0x7fffu + ((u >> 16) & 1u)) >> 16;
  return (unsigned short)u;
}

__device__ inline void gload_lds16(const void* g, void* l) {
  typedef const __attribute__((address_space(1))) unsigned GQ;
  typedef __attribute__((address_space(3))) unsigned LQ;
  __builtin_amdgcn_global_load_lds((GQ*)g, (LQ*)l, 16, 0, 0);
}

// ---- fp32 -> bf16 elementwise ----
__global__ __launch_bounds__(256)
void cvt_bf16(const float* __restrict__ in, unsigned short* __restrict__ out,
              long nelem) {
  long i = ((long)blockIdx.x * 256 + threadIdx.x) * 4;
  if (i >= nelem) return;
  float4 v = *(const float4*)(in + i);
  unsigned long long p = (unsigned long long)f2bf(v.x) |
                         ((unsigned long long)f2bf(v.y) << 16) |
                         ((unsigned long long)f2bf(v.z) << 32) |
                         ((unsigned long long)f2bf(v.w) << 48);
  *(unsigned long long*)(out + i) = p;
}

// ---- fp32 [R][C] -> bf16 [C][R] tiled transpose ----
__global__ __launch_bounds__(256)
void transpose_cvt(const float* __restrict__ in, unsigned short* __restrict__ out,
                   int R, int C) {
  __shared__ float t[32][33];
  const int bx = blockIdx.x * 32;
  const int by = blockIdx.y * 32;
  const int x = threadIdx.x & 31, y = threadIdx.x >> 5;
#pragma unroll
  for (int j = 0; j < 4; ++j)
    t[y * 4 + j][x] = in[(long)(by + y * 4 + j) * C + bx + x];
  __syncthreads();
#pragma unroll
  for (int j = 0; j < 4; ++j)
    out[(long)(bx + y * 4 + j) * R + by + x] = f2bf(t[x][y * 4 + j]);
}

// ---- V^T pre-transpose: qkv fp32 V (rows t, 256 cols) -> VtG bf16 [256][T] ----
__global__ __launch_bounds__(256)
void vt_transpose(const float* __restrict__ qkv, unsigned short* __restrict__ VtG) {
  __shared__ float t[32][33];
  const int t0 = blockIdx.x * 32;
  const int c0 = blockIdx.y * 32;
  const int x = threadIdx.x & 31, y = threadIdx.x >> 5;
#pragma unroll
  for (int j = 0; j < 4; ++j)
    t[y * 4 + j][x] = qkv[(long)(t0 + y * 4 + j) * kNqkv + 4352 + c0 + x];
  __syncthreads();
#pragma unroll
  for (int j = 0; j < 4; ++j)
    VtG[(long)(c0 + y * 4 + j) * kT + t0 + x] = f2bf(t[x][y * 4 + j]);
}

// ---- C[M,N] fp32 = A[M,K]bf16 @ Bt[N,K]bf16^T. 128x128 tile, BK=64. ----
__global__ __launch_bounds__(256)
void gemm_bf16(const unsigned short* __restrict__ A,
               const unsigned short* __restrict__ Bt, float* __restrict__ C,
               int M, int N, int K) {
  __shared__ __align__(16) unsigned short As[128 * 64];
  __shared__ __align__(16) unsigned short Bs[128 * 64];
  const int tid = threadIdx.x;
  const int lane = tid & 63;
  const int w = tid >> 6;
  const int wr = w >> 1, wc = w & 1;
  const int n = lane & 15;
  const int quad = lane >> 4;
  const long bm = (long)blockIdx.x * 128, bn = (long)blockIdx.y * 128;

  floatx4 acc[4][4];
  floatx4 zero = {0.f, 0.f, 0.f, 0.f};
#pragma unroll
  for (int a = 0; a < 4; ++a)
#pragma unroll
    for (int b = 0; b < 4; ++b) acc[a][b] = zero;

  for (int k0 = 0; k0 < K; k0 += 64) {
    __syncthreads();
#pragma unroll
    for (int it = 0; it < 4; ++it) {
      int ci = it * 256 + tid;
      int r = ci >> 3, c = ci & 7;
      int cg = c ^ (r & 7);
      gload_lds16(A + (bm + r) * (long)K + k0 + cg * 8, As + (it * 256 + w * 64) * 8);
      gload_lds16(Bt + (bn + r) * (long)K + k0 + cg * 8, Bs + (it * 256 + w * 64) * 8);
    }
    __syncthreads();

#pragma unroll
    for (int ks = 0; ks < 2; ++ks) {
      short8 af[4], bf[4];
#pragma unroll
      for (int a = 0; a < 4; ++a) {
        int m = wr * 64 + a * 16 + n;
        af[a] = *(const short8*)(As + m * 64 + ((4 * ks + quad) ^ (m & 7)) * 8);
      }
#pragma unroll
      for (int b = 0; b < 4; ++b) {
        int nn = wc * 64 + b * 16 + n;
        bf[b] = *(const short8*)(Bs + nn * 64 + ((4 * ks + quad) ^ (nn & 7)) * 8);
      }
#pragma unroll
      for (int a = 0; a < 4; ++a)
#pragma unroll
        for (int b = 0; b < 4; ++b)
          acc[a][b] = __builtin_amdgcn_mfma_f32_16x16x32_bf16(af[a], bf[b], acc[a][b], 0, 0, 0);
    }
  }
#pragma unroll
  for (int a = 0; a < 4; ++a)
#pragma unroll
    for (int b = 0; b < 4; ++b)
#pragma unroll
      for (int r = 0; r < 4; ++r)
        C[(bm + wr * 64 + a * 16 + quad * 4 + r) * (long)N + bn + wc * 64 + b * 16 + n] =
            acc[a][b][r];
}

// ------------- RMSNorm + RoPE + bf16 pack (q,k only) -------------
__global__ __launch_bounds__(128)
void norm_rope_cvt(float* qkv, const float* __restrict__ cosb,
                   const float* __restrict__ sinb, const float* __restrict__ qw,
                   const float* __restrict__ kw) {
  unsigned short* qkvu = (unsigned short*)qkv;
  const int blk = blockIdx.x;
  const int t = blk / 18;
  const int h = blk % 18;
  const int i = threadIdx.x;

  const bool isq = (h < kH);
  const long base = (long)t * kNqkv + (isq ? h * 2 * kD : kQsz + (h - kH) * kD);
  float x = qkv[base + i];
  float v = x * x;
#pragma unroll
  for (int off = 1; off < 64; off <<= 1) v += __shfl_xor(v, off, 64);
  __shared__ float wsum[2];
  if ((i & 63) == 0) wsum[i >> 6] = v;
  __syncthreads();
  float rms = rsqrtf((wsum[0] + wsum[1]) * (1.0f / kD) + kEps);
  float nv = x * rms * (isq ? qw[i] : kw[i]);
  __shared__ float nb[128];
  nb[i] = nv;
  __syncthreads();
  float rot = (i < 64) ? -nb[i + 64] : nb[i - 64];
  float ro = nv * cosb[t * kD + i] + rot * sinb[t * kD + i];
  if (isq) {
    float g = qkv[base + kD + i];
    qkv[base + kD + i] = 1.0f / (1.0f + __expf(-g));
    qkvu[(long)t * kRowU + 512 * h + i] = f2bf(ro);
  } else {
    qkvu[(long)t * kRowU + 8192 + 256 * (h - kH) + i] = f2bf(ro);
  }
}

// ---------------- bf16 MFMA flash attention v4 ----------------
// Persistent blocks + atomic work queue (heavy-first). Single barrier per
// KV tile: K double-buffered (staged 1 tile ahead, drained by next barrier),
// V single-buffered (staged at iter top, waited via vmcnt(4) after S),
// Ps in its own buffer (wave-private: no barrier). LDS = 64 KB.
__global__ __launch_bounds__(256)
void flash_attn_mfma(const unsigned short* qkvu, const float* qkvf,
                     const unsigned short* VtG, unsigned short* __restrict__ og,
                     int* __restrict__ ctr) {
  __shared__ __align__(16) unsigned short Ks[2][64 * 128];  // K double buffer
  __shared__ __align__(16) unsigned short Vt[128 * 64];     // V^T tile
  __shared__ __align__(16) unsigned short Ps[128 * 64];     // P (wave-private rows)
  __shared__ int s_item;

  const int tid = threadIdx.x;
  const int lane = tid & 63;
  const int w = tid >> 6;
  const int n = lane & 15;
  const int quad = lane >> 4;

  short8 lfrag;  // B-frag: col 0 = ones -> row-sum accumulator
  {
    short o = (n == 0) ? (short)0x3F80 : (short)0;
    lfrag = (short8){o, o, o, o, o, o, o, o};
  }
  floatx4 zero = {0.f, 0.f, 0.f, 0.f};

  while (true) {
    if (tid == 0) s_item = atomicAdd(ctr, 1);
    __syncthreads();  // broadcast item; also drains prev item's LDS traffic
    const int item = s_item;
    if (item >= 512) break;
    const int h = item & 15;
    const int bm = 31 - (item >> 4);  // heavy-first
    const int hk = h >> 3;
    const int q0 = bm * 128;

    short8 qf[2][4];
#pragma unroll
    for (int mt = 0; mt < 2; ++mt) {
      const unsigned short* qrow =
          qkvu + (long)(q0 + 32 * w + 16 * mt + n) * kRowU + 512 * h;
#pragma unroll
      for (int ks = 0; ks < 4; ++ks)
        qf[mt][ks] = *(const short8*)(qrow + 32 * ks + 8 * quad);
    }

    floatx4 O[2][8];
    floatx4 Ol[2];
#pragma unroll
    for (int mt = 0; mt < 2; ++mt) {
      Ol[mt] = zero;
#pragma unroll
      for (int dt = 0; dt < 8; ++dt) O[mt][dt] = zero;
    }

    const int kn_end = 2 * bm + 1;
    // prologue: stage K(0) into buf 0 (chunk swizzle c ^ (r&15))
#pragma unroll
    for (int it = 0; it < 4; ++it) {
      int pc = (w * 4 + it) * 64 + lane;
      int r = pc >> 4, c = pc & 15;
      int lc = c ^ (r & 15);
      gload_lds16(qkvu + (long)(0 * 64 + r) * kRowU + 8192 + 256 * hk + 8 * lc,
                  Ks[0] + (w * 4 + it) * 512);
    }

    int b = 0;
    for (int kn = 0; kn <= kn_end; ++kn, b ^= 1) {
      __syncthreads();  // drains K(kn) staging; frees Vt and Ks[b^1]

      // stage V(kn): 128 d-rows x 64 keys, chunk swizzle c ^ (d&7)  [4 loads]
#pragma unroll
      for (int it = 0; it < 4; ++it) {
        int pc = (w * 4 + it) * 64 + lane;
        int d = pc >> 3, c = pc & 7;
        int lc = c ^ (d & 7);
        gload_lds16(VtG + (long)hk * (128 * kT) + (long)d * kT + kn * 64 + 8 * lc,
                    Vt + (w * 4 + it) * 512);
      }
      // stage K(kn+1) into Ks[b^1] (clamped; redundant restage on last iter)
      {
        int knn = (kn < kn_end) ? (kn + 1) : kn_end;
#pragma unroll
        for (int it = 0; it < 4; ++it) {
          int pc = (w * 4 + it) * 64 + lane;
          int r = pc >> 4, c = pc & 15;
          int lc = c ^ (r & 15);
          gload_lds16(qkvu + (long)(knn * 64 + r) * kRowU + 8192 + 256 * hk + 8 * lc,
                      Ks[b ^ 1] + (w * 4 + it) * 512);
        }
      }

      // S = Q K^T from Ks[b] (staged last iter, drained by this barrier)
      floatx4 S[2][4];
#pragma unroll
      for (int mt = 0; mt < 2; ++mt)
#pragma unroll
        for (int ct = 0; ct < 4; ++ct) S[mt][ct] = zero;
#pragma unroll
      for (int ks = 0; ks < 4; ++ks) {
#pragma unroll
        for (int ct = 0; ct < 4; ++ct) {
          int row = 16 * ct + n;
          short8 kf = *(const short8*)(Ks[b] + row * 128 + ((4 * ks + quad) ^ n) * 8);
          S[0][ct] = __builtin_amdgcn_mfma_f32_16x16x32_bf16(qf[0][ks], kf, S[0][ct], 0, 0, 0);
          S[1][ct] = __builtin_amdgcn_mfma_f32_16x16x32_bf16(qf[1][ks], kf, S[1][ct], 0, 0, 0);
        }
      }

      // p = exp(s*scale); write Ps (own-wave rows; row-swizzled, conflict-free)
      const bool needmask = (kn >= 2 * bm);
      const int jbase = (kn - 2 * bm) * 64;
      const int hi = n >> 3, lo = n & 7;
#pragma unroll
      for (int mt = 0; mt < 2; ++mt) {
#pragma unroll
        for (int r = 0; r < 4; ++r) {
          int prow = 32 * w + 16 * mt + quad * 4 + r;
          float p0 = __expf(S[mt][0][r] * kScale);
          float p1 = __expf(S[mt][1][r] * kScale);
          float p2 = __expf(S[mt][2][r] * kScale);
          float p3 = __expf(S[mt][3][r] * kScale);
          if (needmask) {
            if (jbase + n > prow) p0 = 0.f;
            if (jbase + 16 + n > prow) p1 = 0.f;
            if (jbase + 32 + n > prow) p2 = 0.f;
            if (jbase + 48 + n > prow) p3 = 0.f;
          }
          int sw = prow & 7;
          Ps[prow * 64 + (((0 + hi) ^ sw) << 3) + lo] = f2bf(p0);
          Ps[prow * 64 + (((2 + hi) ^ sw) << 3) + lo] = f2bf(p1);
          Ps[prow * 64 + (((4 + hi) ^ sw) << 3) + lo] = f2bf(p2);
          Ps[prow * 64 + (((6 + hi) ^ sw) << 3) + lo] = f2bf(p3);
        }
      }
      __asm__ volatile("s_waitcnt lgkmcnt(0)" ::: "memory");  // own-wave Ps visible
      __asm__ volatile("s_waitcnt vmcnt(4)" ::: "memory");    // V(kn) landed (K(kn+1) still in flight)

      // O += P V ; Ol += P @ ones
#pragma unroll
      for (int ks = 0; ks < 2; ++ks) {
        int r0 = 32 * w + n, r1 = 32 * w + 16 + n;
        short8 pf0 = *(const short8*)(Ps + r0 * 64 + (((4 * ks + quad) ^ (r0 & 7)) << 3));
        short8 pf1 = *(const short8*)(Ps + r1 * 64 + (((4 * ks + quad) ^ (r1 & 7)) << 3));
        Ol[0] = __builtin_amdgcn_mfma_f32_16x16x32_bf16(pf0, lfrag, Ol[0], 0, 0, 0);
        Ol[1] = __builtin_amdgcn_mfma_f32_16x16x32_bf16(pf1, lfrag, Ol[1], 0, 0, 0);
#pragma unroll
        for (int dt = 0; dt < 8; ++dt) {
          int d = 16 * dt + n;
          short8 vf = *(const short8*)(Vt + d * 64 + (((4 * ks + quad) ^ (d & 7)) << 3));
          O[0][dt] = __builtin_amdgcn_mfma_f32_16x16x32_bf16(pf0, vf, O[0][dt], 0, 0, 0);
          O[1][dt] = __builtin_amdgcn_mfma_f32_16x16x32_bf16(pf1, vf, O[1][dt], 0, 0, 0);
        }
      }
    }

    // epilogue: l broadcast, normalize, gate, store bf16
#pragma unroll
    for (int mt = 0; mt < 2; ++mt) {
#pragma unroll
      for (int r = 0; r < 4; ++r) {
        float l = __shfl(Ol[mt][r], quad << 4, 64);
        float inv = 1.0f / l;
        int row = q0 + 32 * w + 16 * mt + quad * 4 + r;
#pragma unroll
        for (int dt = 0; dt < 8; ++dt) {
          int col = 16 * dt + n;
          float gte = qkvf[(long)row * kNqkv + 256 * h + 128 + col];
          og[(long)row * kHid + 128 * h + col] = f2bf(O[mt][dt][r] * inv * gte);
        }
      }
    }
  }
}

extern "C" void kernel_launch(void* const* d_in, const int* in_sizes, int n_in,
                              void* d_out, int out_size, void* d_ws, size_t ws_size,
                              hipStream_t stream) {
  (void)in_sizes; (void)n_in; (void)out_size; (void)ws_size;
  const float* hs   = (const float*)d_in[0];
  const float* cosb = (const float*)d_in[1];
  const float* sinb = (const float*)d_in[2];
  const float* wqkv = (const float*)d_in[3];
  const float* wo   = (const float*)d_in[4];
  const float* qw   = (const float*)d_in[5];
  const float* kw   = (const float*)d_in[6];
  float* out = (float*)d_out;

  char* ws = (char*)d_ws;
  float* qkv = (float*)ws;                                    // 75.5 MB fp32
  unsigned short* hsb = (unsigned short*)(ws + 75497472);     // 16.8 MB (aliases og)
  unsigned short* og  = hsb;                                  // written after hsb dead
  unsigned short* wt  = (unsigned short*)(ws + 92274688);     // 18.9 MB shared
  unsigned short* VtG = wt;  // aliases dead w_qkv^T during flash (w_o^T written after)
  // work-queue counter: lives in qkv row 0's dead fp32-V slot (only read by
  // vt_transpose, which runs before the memset below).
  int* ctr = (int*)(ws + 17408);

  cvt_bf16<<<dim3(8192), 256, 0, stream>>>(hs, hsb, (long)kT * kHid);
  transpose_cvt<<<dim3(kNqkv / 32, kHid / 32), 256, 0, stream>>>(wqkv, wt, kHid, kNqkv);
  gemm_bf16<<<dim3(kT / 128, kNqkv / 128), 256, 0, stream>>>(hsb, wt, qkv, kT, kNqkv, kHid);
  vt_transpose<<<dim3(kT / 32, 8), 256, 0, stream>>>(qkv, VtG);
  norm_rope_cvt<<<dim3(kT * 18), 128, 0, stream>>>(qkv, cosb, sinb, qw, kw);
  hipMemsetAsync(ctr, 0, 4, stream);
  flash_attn_mfma<<<dim3(512), 256, 0, stream>>>((const unsigned short*)qkv, qkv, VtG, og, ctr);
  transpose_cvt<<<dim3(kHid / 32, kHid / 32), 256, 0, stream>>>(wo, wt, kHid, kHid);
  gemm_bf16<<<dim3(kT / 128, kHid / 128), 256, 0, stream>>>(og, wt, out, kT, kHid, kHid);
}